// Round 7
// baseline (5121.550 us; speedup 1.0000x reference)
//
#include <hip/hip_runtime.h>
#include <hip/hip_fp16.h>

#define TM1   127
#define NE    128
#define NT    1024
#define NB    512            // 2 batches/block; goal: 2 blocks co-resident per CU
#define ROWW  65             // words per preX row; 65 % 32 = 1 -> exact 2-way banks (free)

#if __has_builtin(__builtin_amdgcn_exp2f)
#define EXP2(x) __builtin_amdgcn_exp2f(x)
#else
#define EXP2(x) exp2f(x)
#endif
#define RCP(x) __builtin_amdgcn_rcpf(x)
#define K2 2.885390081777927f   // 2*log2(e): tanh term = 1 - 2*rcp(exp2(K2*x)+1)

__device__ __forceinline__ float fast_sig(float x){ return RCP(1.0f + __expf(-x)); }
__device__ __forceinline__ float fast_tanh(float x){ float e = __expf(2.0f*x); return 1.0f - 2.0f*RCP(e+1.0f); }
__device__ __forceinline__ float blo(unsigned u){ union{unsigned i; float f;} v; v.i = u<<16;           return v.f; }
__device__ __forceinline__ float bhi(unsigned u){ union{unsigned i; float f;} v; v.i = u & 0xffff0000u; return v.f; }
__device__ __forceinline__ float rdlane(float v, int l) {
    union{float f; int i;} a, r; a.f = v;
    r.i = __builtin_amdgcn_readlane(a.i, l);   // l wave-uniform (unrolled literal)
    return r.f;
}

// Pack W1dc (rows 0..255) and Wh into bf16 k-quads in workspace (same work every launch).
__global__ void pack_weights(const float* __restrict__ W1, const float* __restrict__ Wh,
                             uint2* __restrict__ W1q, uint2* __restrict__ Whq) {
    const int t = blockIdx.x*256 + threadIdx.x;
    auto bf16 = [](float f)->unsigned {
        union{float f; unsigned u;} v; v.f = f;
        return (v.u + 0x7fffu + ((v.u>>16)&1u)) >> 16;   // RNE
    };
    if (t < 8192) {                       // W1q[k4][e], k4=0..63 covers k=0..255 ([d;c])
        const int k4 = t >> 7, e = t & 127;
        unsigned a = bf16(W1[(4*k4+0)*NE + e]);
        unsigned b = bf16(W1[(4*k4+1)*NE + e]);
        unsigned c = bf16(W1[(4*k4+2)*NE + e]);
        unsigned d = bf16(W1[(4*k4+3)*NE + e]);
        W1q[k4*128 + e] = make_uint2(a | (b<<16), c | (d<<16));
    } else if (t < 24576) {               // Whq[k4][j], k4=0..31 covers k=0..127
        const int t2 = t - 8192;
        const int k4 = t2 >> 9, j = t2 & 511;
        unsigned a = bf16(Wh[(4*k4+0)*512 + j]);
        unsigned b = bf16(Wh[(4*k4+1)*512 + j]);
        unsigned c = bf16(Wh[(4*k4+2)*512 + j]);
        unsigned d = bf16(Wh[(4*k4+3)*512 + j]);
        Whq[k4*512 + j] = make_uint2(a | (b<<16), c | (d<<16));
    }
}

__global__ __launch_bounds__(NT)
void decoder_kernel(const float* __restrict__ Xg,     // (1024,127,128)
                    const float* __restrict__ yprev,  // (1024,127)
                    const float* __restrict__ W1,     // (384,128)
                    const float* __restrict__ b1,
                    const float* __restrict__ W2,     // (128)
                    const float* __restrict__ b2v,
                    const float* __restrict__ Wfc,    // (129)
                    const float* __restrict__ bfcv,
                    const float* __restrict__ Wx,     // (512)
                    const float* __restrict__ blv,    // (512)
                    const float* __restrict__ Wf,     // (256)
                    const float* __restrict__ bfv,
                    const uint2* __restrict__ W1q,    // packed bf16 [64][128]
                    const uint2* __restrict__ Whq,    // packed bf16 [32][512]
                    float* __restrict__ out)          // (1024)
{
    // LDS budget: 66560+2048+1088+4096+1024+1024+1024+1024+32+64 = 77984 B
    // 2 blocks x ~78KB = ~156.7KB <= 160KB-with-reserve -> co-residency target
    __shared__ __align__(16) unsigned preXu[2*128*ROWW]; // fp16 pairs: K2*(b1+X@W1x)
    __shared__ __align__(16) float sdc  [512];           // [b*256 + (d|c)]
    __shared__ __align__(16) unsigned uwhu[272];         // [b*136+q*34+j]: half2(K2*u, -2*W2)
    __shared__ __align__(16) float zsc  [1024];          // [b*512+j] d@Wh; epilogue scratch
    __shared__ __align__(16) float XWfcs[256];
    __shared__ __align__(16) float betas[256];
    __shared__ __align__(16) uint2 wxq  [128];           // bf16 Wx quads (i,f,g,o)
    __shared__ __align__(16) uint2 blq  [128];           // bf16 bl quads
    __shared__ float params[8];                          // 0:wfcy 1:bfc 2:bf 4..7:pinit[q]
    __shared__ float swv[16];

    const int tid  = (int)threadIdx.x;
    const int lane = tid & 63;
    const int b0   = (int)blockIdx.x * 2;
    const int eA = tid >> 3, oA = tid & 7;                        // A + preamble
    const int wbC = tid >> 9, jC = tid & 511;                     // C (wave-uniform batch)
    const int bB = tid >> 9, tB = (tid >> 2) & 127, qB = tid & 3; // B
    const int wv = tid >> 6;

    auto bf16r = [](float f)->unsigned {
        union{float f; unsigned u;} v; v.f = f;
        return (v.u + 0x7fffu + ((v.u>>16)&1u)) >> 16;
    };
    __half* preXhh = (__half*)preXu;
    __half* uwhh   = (__half*)uwhu;

    // ---- init (nothing loop-persistent in VGPRs) ----
    if (tid < 128) {
        wxq[tid] = make_uint2(bf16r(Wx[tid])     | (bf16r(Wx[128+tid])<<16),
                              bf16r(Wx[256+tid]) | (bf16r(Wx[384+tid])<<16));
        blq[tid] = make_uint2(bf16r(blv[tid])     | (bf16r(blv[128+tid])<<16),
                              bf16r(blv[256+tid]) | (bf16r(blv[384+tid])<<16));
    }
    if (tid == 0) { params[0] = Wfc[NE]; params[1] = bfcv[0]; params[2] = bfv[0]; }
    if (tid >= 4 && tid < 8) {                       // pinit[q] = b2/4 + sum W2[q-slice]
        const int q = tid - 4;
        float s = b2v[0] * 0.25f;
        for (int i = 0; i < 32; ++i) s += W2[q*32 + i];
        params[4 + q] = s;
    }
    if (tid < 512) {
        const int b = tid >> 8, g = tid & 255;
        sdc[b*256 + g] = Xg[(size_t)(b0+b)*TM1*NE];  // d0 = c0 = X[b,0,0]
    }
    if (tid < 256) {
        const int b = tid >> 7, g = tid & 127;
        betas[tid] = 0.0f;
        // -2*W2 into uwhu high halves (phase A later writes only the low fp16 halves)
        uwhh[2*(b*136 + (g>>5)*34 + (g&31)) + 1] = __float2half(-2.0f * W2[g]);
        float xw = 0.0f;                              // XWfc[t'] = X[t'].Wfc[:128]
        if (g < TM1) {
            const float4* xr = (const float4*)(Xg + ((size_t)(b0+b)*TM1 + g)*NE);
            #pragma unroll 4
            for (int i = 0; i < 32; ++i) {
                const float4 x = xr[i];
                const float4 w = *(const float4*)&Wfc[i*4];
                xw = fmaf(x.x,w.x, fmaf(x.y,w.y, fmaf(x.z,w.z, fmaf(x.w,w.w, xw))));
            }
        }
        XWfcs[tid] = xw;                              // row 127 -> 0
    }
    if (tid < 260) {                                  // neutral row 127 (never used; keep finite)
        const int b = tid / 130, j = tid - b*130;
        preXhh[(b*128 + 127)*2*ROWW + j] = __float2half(0.0f);
    }

    // ---- preamble: preX fp16 straight from global (8-lane bcast segments, no barriers) ----
    {
        float w1x[16];
        #pragma unroll
        for (int m = 0; m < 16; ++m) w1x[m] = W1[(256 + oA*16 + m)*NE + eA];
        const float b1r = b1[eA];
        for (int b = 0; b < 2; ++b) {
            const float* Xbase = Xg + (size_t)(b0+b)*TM1*NE;
            for (int tp = 0; tp < TM1; ++tp) {
                const float4* xr = (const float4*)(Xbase + tp*NE + oA*16);
                float s0 = 0.f, s1 = 0.f;
                #pragma unroll
                for (int q = 0; q < 4; ++q) {
                    const float4 x = xr[q];
                    float& s = (q & 1) ? s1 : s0;
                    s = fmaf(w1x[q*4+0],x.x, fmaf(w1x[q*4+1],x.y,
                        fmaf(w1x[q*4+2],x.z, fmaf(w1x[q*4+3],x.w, s))));
                }
                float s = s0 + s1;
                s += __shfl_xor(s,1); s += __shfl_xor(s,2); s += __shfl_xor(s,4);
                if (oA == 0)
                    preXhh[(b*128+tp)*2*ROWW + eA] = __float2half(K2*(s + b1r));
            }
        }
    }
    __syncthreads();

    const float4* sdc4 = (const float4*)sdc;

    for (int t = 0; t < TM1; ++t) {
        // per-step y (2 scalars/batch; L1-hot; carried in VGPR across barriers)
        float yv = 0.0f;
        if (tid < 256) yv = yprev[(size_t)(b0 + (tid>>7))*TM1 + t];

        // ==== A: u[b][e], 8-way k-split; rotated quads -> all 32 banks, 8-lane bcast ====
        {
            float a0=0.f, a0b=0.f, a1=0.f, a1b=0.f;
            #pragma unroll
            for (int i = 0; i < 8; ++i) {
                const int k4 = oA*8 + ((i + oA) & 7);
                const uint2 w = W1q[k4*128 + eA];
                const float wa=blo(w.x), wb=bhi(w.x), wc=blo(w.y), wd=bhi(w.y);
                const float4 v0 = sdc4[k4];
                const float4 v1 = sdc4[64 + k4];
                if (i & 1) {
                    a0b = fmaf(wa,v0.x,fmaf(wb,v0.y,fmaf(wc,v0.z,fmaf(wd,v0.w,a0b))));
                    a1b = fmaf(wa,v1.x,fmaf(wb,v1.y,fmaf(wc,v1.z,fmaf(wd,v1.w,a1b))));
                } else {
                    a0  = fmaf(wa,v0.x,fmaf(wb,v0.y,fmaf(wc,v0.z,fmaf(wd,v0.w,a0))));
                    a1  = fmaf(wa,v1.x,fmaf(wb,v1.y,fmaf(wc,v1.z,fmaf(wd,v1.w,a1))));
                }
            }
            float s0 = a0 + a0b, s1 = a1 + a1b;
            s0 += __shfl_xor(s0,1); s0 += __shfl_xor(s0,2); s0 += __shfl_xor(s0,4);
            s1 += __shfl_xor(s1,1); s1 += __shfl_xor(s1,2); s1 += __shfl_xor(s1,4);
            if (oA == 0) {                             // 16-bit writes: keep -2W2 high halves
                const int ui = (eA >> 5)*34 + (eA & 31);
                uwhh[2*ui]           = __float2half(K2*s0);
                uwhh[2*(136 + ui)]   = __float2half(K2*s1);
            }
        }
        // ==== C: z[b][j] = d@Wh, LDS-free readlane broadcast, 4 indep chains ====
        {
            const float dv0 = sdc[wbC*256 + lane];        // d[0..63]
            const float dv1 = sdc[wbC*256 + 64 + lane];   // d[64..127]
            float z0=0.f, z1=0.f, z2=0.f, z3=0.f;
            #pragma unroll
            for (int k4 = 0; k4 < 8; ++k4) {
                const uint2 w = Whq[k4*512 + jC];
                const int k = 4*k4;
                z0 = fmaf(blo(w.x), rdlane(dv0, k+0), z0);
                z0 = fmaf(bhi(w.x), rdlane(dv0, k+1), z0);
                z0 = fmaf(blo(w.y), rdlane(dv0, k+2), z0);
                z0 = fmaf(bhi(w.y), rdlane(dv0, k+3), z0);
            }
            #pragma unroll
            for (int k4 = 8; k4 < 16; ++k4) {
                const uint2 w = Whq[k4*512 + jC];
                const int k = 4*k4;
                z1 = fmaf(blo(w.x), rdlane(dv0, k+0), z1);
                z1 = fmaf(bhi(w.x), rdlane(dv0, k+1), z1);
                z1 = fmaf(blo(w.y), rdlane(dv0, k+2), z1);
                z1 = fmaf(bhi(w.y), rdlane(dv0, k+3), z1);
            }
            #pragma unroll
            for (int k4 = 16; k4 < 24; ++k4) {
                const uint2 w = Whq[k4*512 + jC];
                const int k = 4*k4 - 64;
                z2 = fmaf(blo(w.x), rdlane(dv1, k+0), z2);
                z2 = fmaf(bhi(w.x), rdlane(dv1, k+1), z2);
                z2 = fmaf(blo(w.y), rdlane(dv1, k+2), z2);
                z2 = fmaf(bhi(w.y), rdlane(dv1, k+3), z2);
            }
            #pragma unroll
            for (int k4 = 24; k4 < 32; ++k4) {
                const uint2 w = Whq[k4*512 + jC];
                const int k = 4*k4 - 64;
                z3 = fmaf(blo(w.x), rdlane(dv1, k+0), z3);
                z3 = fmaf(bhi(w.x), rdlane(dv1, k+1), z3);
                z3 = fmaf(blo(w.y), rdlane(dv1, k+2), z3);
                z3 = fmaf(bhi(w.y), rdlane(dv1, k+3), z3);
            }
            zsc[wbC*512 + jC] = (z0 + z1) + (z2 + z3);
        }
        __syncthreads();                                   // S1

        // ==== B: beta[b][t'] quarter-rows; stride-65 b32 reads (2-way, free) ====
        {
            const unsigned* rowp = preXu + (bB*128 + tB)*ROWW + qB*16;
            const unsigned* uwp  = uwhu + bB*136 + qB*34;
            float acc0 = params[4 + qB], acc1 = 0.f, acc2 = 0.f, acc3 = 0.f;
            #pragma unroll
            for (int i = 0; i < 16; i += 4) {
                #pragma unroll
                for (int m = 0; m < 4; ++m) {
                    const unsigned pw = rowp[i+m];
                    const uint2 uu = *(const uint2*)&uwp[2*(i+m)];
                    const __half2 px2 = *(const __half2*)&pw;
                    const __half2 u0  = *(const __half2*)&uu.x;  // (K2u, -2W2) e=q*32+2(i+m)
                    const __half2 u1  = *(const __half2*)&uu.y;
                    float& a = (m==0)?acc0:(m==1)?acc1:(m==2)?acc2:acc3;
                    a = fmaf(__high2float(u0),
                             RCP(EXP2(__low2float(px2)  + __low2float(u0)) + 1.0f), a);
                    a = fmaf(__high2float(u1),
                             RCP(EXP2(__high2float(px2) + __low2float(u1)) + 1.0f), a);
                }
            }
            float pb = (acc0 + acc1) + (acc2 + acc3);
            pb += __shfl_xor(pb,1); pb += __shfl_xor(pb,2);  // sum over 4 quarters
            if (t == TM1-1 && qB == 0 && tB < TM1) betas[bB*128 + tB] = pb;
            float prod = pb * XWfcs[bB*128 + tB];            // row 127 -> *0
            prod += __shfl_xor(prod,4);  prod += __shfl_xor(prod,8);
            prod += __shfl_xor(prod,16); prod += __shfl_xor(prod,32);
            if ((tid & 63) == 0) swv[wv] = prod;
        }
        __syncthreads();                                   // S2

        // ==== gates (256 threads) ====
        if (tid < 256) {
            const int b = tid >> 7, g = tid & 127;
            const float ssum = ((swv[b*8+0]+swv[b*8+1])+(swv[b*8+2]+swv[b*8+3]))
                             + ((swv[b*8+4]+swv[b*8+5])+(swv[b*8+6]+swv[b*8+7]));
            const float ytl = fmaf(yv, params[0], ssum + params[1]);
            const uint2 wq = wxq[g], bq = blq[g];
            const float zi = fmaf(ytl, blo(wq.x), blo(bq.x)) + zsc[b*512 +       g];
            const float zf = fmaf(ytl, bhi(wq.x), bhi(bq.x)) + zsc[b*512 + 128 + g];
            const float zg = fmaf(ytl, blo(wq.y), blo(bq.y)) + zsc[b*512 + 256 + g];
            const float zo = fmaf(ytl, bhi(wq.y), bhi(bq.y)) + zsc[b*512 + 384 + g];
            const float c_old = sdc[b*256 + 128 + g];
            const float cn = fast_sig(zf)*c_old + fast_sig(zi)*fast_tanh(zg);
            const float dn = fast_sig(zo)*fast_tanh(cn);
            sdc[b*256 + g] = dn; sdc[b*256 + 128 + g] = cn;
        }
        __syncthreads();                                   // S3
    }

    // ---- epilogue: final ctx from betas + global X, then out ----
    if (tid < 256) {
        const int b = tid >> 7, e = tid & 127;
        const float* Xb = Xg + (size_t)(b0+b)*TM1*NE + e;
        float cacc = 0.0f;
        #pragma unroll 4
        for (int tp = 0; tp < TM1; ++tp)
            cacc = fmaf(betas[b*128 + tp], Xb[(size_t)tp*NE], cacc);
        zsc[tid] = fmaf(sdc[b*256 + e], Wf[e], cacc * Wf[128 + e]);
    }
    __syncthreads();
    if (tid < 2) {
        float s = 0.0f;
        for (int i = 0; i < 128; ++i) s += zsc[tid*128 + i];
        out[b0 + tid] = s + params[2];
    }
}

extern "C" void kernel_launch(void* const* d_in, const int* in_sizes, int n_in,
                              void* d_out, int out_size, void* d_ws, size_t ws_size,
                              hipStream_t stream) {
    (void)in_sizes; (void)n_in; (void)ws_size; (void)out_size;
    const float* Xg    = (const float*)d_in[0];
    const float* yprev = (const float*)d_in[1];
    const float* W1    = (const float*)d_in[2];
    const float* b1    = (const float*)d_in[3];
    const float* W2    = (const float*)d_in[4];
    const float* b2    = (const float*)d_in[5];
    const float* Wfc   = (const float*)d_in[6];
    const float* bfc   = (const float*)d_in[7];
    const float* Wx    = (const float*)d_in[8];
    const float* Wh    = (const float*)d_in[9];
    const float* bl    = (const float*)d_in[10];
    const float* Wf    = (const float*)d_in[11];
    const float* bf    = (const float*)d_in[12];

    uint2* W1q = (uint2*)d_ws;                         // 64 KB
    uint2* Whq = (uint2*)((char*)d_ws + 65536);        // 128 KB

    pack_weights<<<96, 256, 0, stream>>>(W1, Wh, W1q, Whq);
    decoder_kernel<<<NB, NT, 0, stream>>>(
        Xg, yprev, W1, b1, W2, b2, Wfc, bfc, Wx, bl, Wf, bf, W1q, Whq, (float*)d_out);
}

// Round 8
// 1663.111 us; speedup vs baseline: 3.0795x; 3.0795x over previous
//
#include <hip/hip_runtime.h>
#include <hip/hip_fp16.h>

#define TM1   127
#define NE    128
#define NT    1024
#define NB    256            // 4 batches/block, 1 block/CU
#define ROWW  65             // uint words per E row (128 fp16 + pad); 65%32=1 -> 2-way banks

#if __has_builtin(__builtin_amdgcn_exp2f)
#define EXP2(x) __builtin_amdgcn_exp2f(x)
#else
#define EXP2(x) exp2f(x)
#endif
#define RCP(x) __builtin_amdgcn_rcpf(x)
#define K2 2.885390081777927f   // 2*log2(e); tanh(x) = 1 - 2*rcp(exp2(K2 x)+1)

__device__ __forceinline__ float fast_sig(float x){ return RCP(1.0f + __expf(-x)); }
__device__ __forceinline__ float fast_tanh(float x){ float e = __expf(2.0f*x); return 1.0f - 2.0f*RCP(e+1.0f); }
__device__ __forceinline__ float blo(unsigned u){ union{unsigned i; float f;} v; v.i = u<<16;           return v.f; }
__device__ __forceinline__ float bhi(unsigned u){ union{unsigned i; float f;} v; v.i = u & 0xffff0000u; return v.f; }

// Pack W1dc rows 0..255 as f32 k-quads (float4) and Wh as bf16 k-quads (uint2).
__global__ void pack_weights(const float* __restrict__ W1, const float* __restrict__ Wh,
                             float4* __restrict__ W1p, uint2* __restrict__ Whq) {
    const int t = blockIdx.x*256 + threadIdx.x;
    auto bf16 = [](float f)->unsigned {
        union{float f; unsigned u;} v; v.f = f;
        return (v.u + 0x7fffu + ((v.u>>16)&1u)) >> 16;   // RNE
    };
    if (t < 8192) {                       // W1p[k4*128+e], k4=0..63 covers k=0..255 ([d;c])
        const int k4 = t >> 7, e = t & 127;
        W1p[t] = make_float4(W1[(4*k4+0)*NE + e], W1[(4*k4+1)*NE + e],
                             W1[(4*k4+2)*NE + e], W1[(4*k4+3)*NE + e]);
    } else if (t < 24576) {               // Whq[k4*512+j], k4=0..31 covers k=0..127
        const int t2 = t - 8192;
        const int k4 = t2 >> 9, j = t2 & 511;
        unsigned a = bf16(Wh[(4*k4+0)*512 + j]);
        unsigned b = bf16(Wh[(4*k4+1)*512 + j]);
        unsigned c = bf16(Wh[(4*k4+2)*512 + j]);
        unsigned d = bf16(Wh[(4*k4+3)*512 + j]);
        Whq[k4*512 + j] = make_uint2(a | (b<<16), c | (d<<16));
    }
}

__global__ __launch_bounds__(NT)
void decoder_kernel(const float* __restrict__ Xg,     // (1024,127,128)
                    const float* __restrict__ yprev,  // (1024,127)
                    const float* __restrict__ W1,     // (384,128)
                    const float* __restrict__ b1,
                    const float* __restrict__ W2,     // (128)
                    const float* __restrict__ b2v,
                    const float* __restrict__ Wfc,    // (129)
                    const float* __restrict__ bfcv,
                    const float* __restrict__ Wx,     // (512)
                    const float* __restrict__ blv,    // (512)
                    const float* __restrict__ Wf,     // (256)
                    const float* __restrict__ bfv,
                    const float4* __restrict__ W1p,   // f32 quads [64][128]
                    const uint2* __restrict__ Whq,    // bf16 quads [32][512]
                    float* __restrict__ out)          // (1024)
{
    // 133120+4096+4096+8192+2048+2048+2048+2048+2048+512+32+64 = 160352 B (<=163840)
    __shared__ __align__(16) unsigned Eu [4*128*ROWW]; // fp16 exp2(K2*(b1+X@W1x))
    __shared__ __align__(16) float  sdc  [1024];       // [b*256 + (d|c)]
    __shared__ __align__(16) float2 uws  [512];        // [b*128+e]: (exp2(K2 u), -2*W2[e])
    __shared__ __align__(16) float  zsc  [2048];       // [b*512+j] d@Wh; epilogue scratch
    __shared__ __align__(16) float  XWfcs[512];
    __shared__ __align__(16) float  betas[512];
    __shared__ __align__(16) float  ys   [512];
    __shared__ __align__(16) float4 wxf4 [128];
    __shared__ __align__(16) float4 blf4 [128];
    __shared__ float w2m2[128];
    __shared__ float params[8];                        // 0:wfcy 1:bfc 2:bf 4,5:pinit[h]
    __shared__ float swv[16];

    const int tid  = (int)threadIdx.x;
    const int lane = tid & 63;
    const int wave = tid >> 6;
    const int b0   = (int)blockIdx.x * 4;

    const float4* sdc4 = (const float4*)sdc;
    __half* Eh = (__half*)Eu;

    // ---- init (nothing loop-persistent in VGPRs) ----
    if (tid < 128) {
        w2m2[tid] = -2.0f * W2[tid];
        wxf4[tid] = make_float4(Wx[tid],  Wx[128+tid],  Wx[256+tid],  Wx[384+tid]);
        blf4[tid] = make_float4(blv[tid], blv[128+tid], blv[256+tid], blv[384+tid]);
    }
    if (tid == 0) { params[0] = Wfc[NE]; params[1] = bfcv[0]; params[2] = bfv[0]; }
    if (tid == 4 || tid == 5) {                      // pinit[h] = b2/2 + sum W2[h-half]
        const int h = tid - 4;
        float s = b2v[0] * 0.5f;
        for (int i = 0; i < 64; ++i) s += W2[h*64 + i];
        params[4 + h] = s;
    }
    {   const int b = tid >> 8;                      // d0 = c0 = X[b,0,0]
        sdc[tid] = Xg[(size_t)(b0+b)*TM1*NE];
    }
    if (tid < 512) {
        const int b = tid >> 7, g = tid & 127;
        ys[tid] = (g < TM1) ? yprev[(size_t)(b0+b)*TM1 + g] : 0.0f;
        float xw = 0.0f;                             // XWfc[t'] = X[t'].Wfc[:128]
        if (g < TM1) {
            const float4* xr = (const float4*)(Xg + ((size_t)(b0+b)*TM1 + g)*NE);
            #pragma unroll 4
            for (int i = 0; i < 32; ++i) {
                const float4 x = xr[i];
                const float4 w = *(const float4*)&Wfc[i*4];
                xw = fmaf(x.x,w.x, fmaf(x.y,w.y, fmaf(x.z,w.z, fmaf(x.w,w.w, xw))));
            }
        }
        XWfcs[tid] = xw;                             // row 127 -> 0
    }
    if (tid < 260) {                                 // E row 127 = 0 -> term = w2 const; masked
        const int b = tid / 65, m = tid - b*65;      //   downstream by XWfc=0 / betas skip
        Eu[(b*128 + 127)*ROWW + m] = 0u;
    }

    // ---- preamble: E = exp2(K2*(b1 + X@W1x)) as fp16 ----
    {
        const int eA = tid >> 3, oA = tid & 7;
        float w1x[16];
        #pragma unroll
        for (int m = 0; m < 16; ++m) w1x[m] = W1[(256 + oA*16 + m)*NE + eA];
        const float b1r = b1[eA];
        for (int b = 0; b < 4; ++b) {
            const float* Xbase = Xg + (size_t)(b0+b)*TM1*NE;
            for (int tp = 0; tp < TM1; ++tp) {
                const float4* xr = (const float4*)(Xbase + tp*NE + oA*16);
                float s0 = 0.f, s1 = 0.f;
                #pragma unroll
                for (int q = 0; q < 4; ++q) {
                    const float4 x = xr[q];
                    float& s = (q & 1) ? s1 : s0;
                    s = fmaf(w1x[q*4+0],x.x, fmaf(w1x[q*4+1],x.y,
                        fmaf(w1x[q*4+2],x.z, fmaf(w1x[q*4+3],x.w, s))));
                }
                float s = s0 + s1;
                s += __shfl_xor(s,1); s += __shfl_xor(s,2); s += __shfl_xor(s,4);
                if (oA == 0)
                    Eh[(b*128+tp)*2*ROWW + eA] = __float2half(EXP2(K2*(s + b1r)));
            }
        }
    }
    __syncthreads();

    for (int t = 0; t < TM1; ++t) {
        // ==== phase A: waves 0-3 -> u (all 4 batches); waves 4-11 -> z ====
        if (wave < 4) {
            const int el = lane >> 1, kh = lane & 1;   // kh: d-half vs c-half of k
            const int e  = wave*32 + el;
            float a0=0.f, a1=0.f, a2=0.f, a3=0.f;
            #pragma unroll 2
            for (int k4 = 0; k4 < 32; ++k4) {
                const float4 wv = W1p[(kh*32 + k4)*128 + e];
                const float4 d0 = sdc4[       kh*32 + k4];   // 2 bcast addrs/instr: free
                const float4 d1 = sdc4[ 64 +  kh*32 + k4];
                const float4 d2 = sdc4[128 +  kh*32 + k4];
                const float4 d3 = sdc4[192 +  kh*32 + k4];
                a0 = fmaf(wv.x,d0.x,fmaf(wv.y,d0.y,fmaf(wv.z,d0.z,fmaf(wv.w,d0.w,a0))));
                a1 = fmaf(wv.x,d1.x,fmaf(wv.y,d1.y,fmaf(wv.z,d1.z,fmaf(wv.w,d1.w,a1))));
                a2 = fmaf(wv.x,d2.x,fmaf(wv.y,d2.y,fmaf(wv.z,d2.z,fmaf(wv.w,d2.w,a2))));
                a3 = fmaf(wv.x,d3.x,fmaf(wv.y,d3.y,fmaf(wv.z,d3.z,fmaf(wv.w,d3.w,a3))));
            }
            a0 += __shfl_xor(a0,1); a1 += __shfl_xor(a1,1);
            a2 += __shfl_xor(a2,1); a3 += __shfl_xor(a3,1);
            if (kh == 0) {
                const float w2 = w2m2[e];
                uws[      e] = make_float2(EXP2(K2*a0), w2);
                uws[128 + e] = make_float2(EXP2(K2*a1), w2);
                uws[256 + e] = make_float2(EXP2(K2*a2), w2);
                uws[384 + e] = make_float2(EXP2(K2*a3), w2);
            }
        } else if (wave < 12) {
            const int j = (wave - 4)*64 + lane;
            float a0=0.f, a1=0.f, a2=0.f, a3=0.f;
            #pragma unroll 2
            for (int k4 = 0; k4 < 32; ++k4) {
                const uint2 wq = Whq[k4*512 + j];
                const float wa=blo(wq.x), wb=bhi(wq.x), wc=blo(wq.y), wd=bhi(wq.y);
                const float4 d0 = sdc4[       k4];           // uniform addr: broadcast
                const float4 d1 = sdc4[ 64 +  k4];
                const float4 d2 = sdc4[128 +  k4];
                const float4 d3 = sdc4[192 +  k4];
                a0 = fmaf(wa,d0.x,fmaf(wb,d0.y,fmaf(wc,d0.z,fmaf(wd,d0.w,a0))));
                a1 = fmaf(wa,d1.x,fmaf(wb,d1.y,fmaf(wc,d1.z,fmaf(wd,d1.w,a1))));
                a2 = fmaf(wa,d2.x,fmaf(wb,d2.y,fmaf(wc,d2.z,fmaf(wd,d2.w,a2))));
                a3 = fmaf(wa,d3.x,fmaf(wb,d3.y,fmaf(wc,d3.z,fmaf(wd,d3.w,a3))));
            }
            zsc[       j] = a0; zsc[ 512 + j] = a1;
            zsc[1024 + j] = a2; zsc[1536 + j] = a3;
        }
        __syncthreads();                               // S1

        // ==== phase B: beta terms, 3 ops each: v=fma(E,EU,1); p=fma(w2,rcp(v),p) ====
        {
            const int bB = tid >> 8, tq = (tid >> 6) & 3;
            const int tp = tq*32 + (lane >> 1), h = lane & 1;
            const unsigned* Erow = Eu + (bB*128 + tp)*ROWW + h*32;
            const float4* uw4 = (const float4*)(uws + bB*128 + h*64);
            float p0 = params[4 + h], p1 = 0.f;
            #pragma unroll 4
            for (int i = 0; i < 32; ++i) {
                const unsigned ew = Erow[i];                 // 2-way banks: free
                const float4 uw = uw4[i];                    // (EU0,w20,EU1,w21), 2 bcast
                const __half2 e2 = *(const __half2*)&ew;
                const float v0 = fmaf(__low2float (e2), uw.x, 1.0f);
                const float v1 = fmaf(__high2float(e2), uw.z, 1.0f);
                p0 = fmaf(uw.y, RCP(v0), p0);
                p1 = fmaf(uw.w, RCP(v1), p1);
            }
            float pb = p0 + p1;
            pb += __shfl_xor(pb, 1);                         // h-merge: full row sum
            if (t == TM1-1 && h == 0 && tp < TM1) betas[bB*128 + tp] = pb;
            float prod = pb * XWfcs[bB*128 + tp];            // row 127 -> *0
            prod += __shfl_xor(prod, 2);  prod += __shfl_xor(prod, 4);
            prod += __shfl_xor(prod, 8);  prod += __shfl_xor(prod, 16);
            prod += __shfl_xor(prod, 32);
            if (lane == 0) swv[wave] = prod;
        }
        __syncthreads();                               // S2

        // ==== gates (512 threads) ====
        if (tid < 512) {
            const int b = tid >> 7, g = tid & 127;
            const float ssum = (swv[b*4] + swv[b*4+1]) + (swv[b*4+2] + swv[b*4+3]);
            const float ytl  = fmaf(ys[b*128 + t], params[0], ssum + params[1]);
            const float4 wx = wxf4[g], bl = blf4[g];
            const float zi = fmaf(ytl, wx.x, bl.x) + zsc[b*512 +       g];
            const float zf = fmaf(ytl, wx.y, bl.y) + zsc[b*512 + 128 + g];
            const float zg = fmaf(ytl, wx.z, bl.z) + zsc[b*512 + 256 + g];
            const float zo = fmaf(ytl, wx.w, bl.w) + zsc[b*512 + 384 + g];
            const float c_old = sdc[b*256 + 128 + g];
            const float cn = fast_sig(zf)*c_old + fast_sig(zi)*fast_tanh(zg);
            const float dn = fast_sig(zo)*fast_tanh(cn);
            sdc[b*256 + g] = dn; sdc[b*256 + 128 + g] = cn;
        }
        __syncthreads();                               // S3
    }

    // ---- epilogue: final ctx from betas + global X, then out ----
    if (tid < 512) {
        const int b = tid >> 7, e = tid & 127;
        const float* Xb = Xg + (size_t)(b0+b)*TM1*NE + e;
        float cacc = 0.0f;
        #pragma unroll 4
        for (int tp = 0; tp < TM1; ++tp)
            cacc = fmaf(betas[b*128 + tp], Xb[(size_t)tp*NE], cacc);
        zsc[tid] = fmaf(sdc[b*256 + e], Wf[e], cacc * Wf[128 + e]);
    }
    __syncthreads();
    if (tid < 4) {
        float s = 0.0f;
        for (int i = 0; i < 128; ++i) s += zsc[tid*128 + i];
        out[b0 + tid] = s + params[2];
    }
}

extern "C" void kernel_launch(void* const* d_in, const int* in_sizes, int n_in,
                              void* d_out, int out_size, void* d_ws, size_t ws_size,
                              hipStream_t stream) {
    (void)in_sizes; (void)n_in; (void)ws_size; (void)out_size;
    const float* Xg    = (const float*)d_in[0];
    const float* yprev = (const float*)d_in[1];
    const float* W1    = (const float*)d_in[2];
    const float* b1    = (const float*)d_in[3];
    const float* W2    = (const float*)d_in[4];
    const float* b2    = (const float*)d_in[5];
    const float* Wfc   = (const float*)d_in[6];
    const float* bfc   = (const float*)d_in[7];
    const float* Wx    = (const float*)d_in[8];
    const float* Wh    = (const float*)d_in[9];
    const float* bl    = (const float*)d_in[10];
    const float* Wf    = (const float*)d_in[11];
    const float* bf    = (const float*)d_in[12];

    float4* W1p = (float4*)d_ws;                       // 128 KB
    uint2*  Whq = (uint2*)((char*)d_ws + 131072);      // 128 KB

    pack_weights<<<96, 256, 0, stream>>>(W1, Wh, W1p, Whq);
    decoder_kernel<<<NB, NT, 0, stream>>>(
        Xg, yprev, W1, b1, W2, b2, Wfc, bfc, Wx, bl, Wf, bf, W1p, Whq, (float*)d_out);
}